// Round 5
// baseline (481.201 us; speedup 1.0000x reference)
//
#include <hip/hip_runtime.h>
#include <math.h>

#define EPSF 1e-12f

// N=64, C=512, P=1600, K=64
// Fused v2: grid (10 pgroups x 64 n), 256 thr, chunk = 32 p, 5 chunks.
// GEMM1 A-frags from global x [c][p] (coalesced, HBM once); GEMM2 B-frags
// re-read the same 512x32 slab from global (L2-hot). LDS only for a' (5 KB)
// + softmax cross-wave partials. acc D[64k][512c] lives in VGPRs across chunks.
// ws: Wb bf16 @0 | asum @65,536 | rn2 @81,920 | gn @98,304

typedef short bf16x8 __attribute__((ext_vector_type(8)));
typedef float f32x4  __attribute__((ext_vector_type(4)));

__device__ __forceinline__ ushort f2b(float x) {
    unsigned u = __float_as_uint(x);
    return (ushort)((u + 0x7fffu + ((u >> 16) & 1u)) >> 16);
}

// ------------------------------------------------- K0: Wb[k][c] = bf16(W)
__global__ __launch_bounds__(256) void k0_wb(const float* __restrict__ W,
                                             ushort* __restrict__ Wb) {
    int i = blockIdx.x * 256 + threadIdx.x;
    if (i < 64 * 512) Wb[i] = f2b(W[i]);
}

// ------------------------------------------------- fused v2
#define ASTR 40   // a' LDS p-stride (elems): 80 B rows, 16-B aligned

__global__ __launch_bounds__(256, 2) void k_fused2(const float* __restrict__ x,
                                                   const ushort* __restrict__ Wb,
                                                   float* __restrict__ out,
                                                   float* __restrict__ asum) {
    const int n  = blockIdx.y;
    const int pg = blockIdx.x;            // 0..9, 160 p each
    const int w = threadIdx.x >> 6, lane = threadIdx.x & 63;
    const int q = lane >> 4, l15 = lane & 15;
    const int pt = w & 1;                 // p-subtile for GEMM1
    const int kh = w >> 1;                // k-half (32 clusters) for GEMM1

    __shared__ float  smx[2][2][16];      // [kh][pt][row]
    __shared__ float  ssm[2][2][16];
    __shared__ ushort as_[64 * ASTR] __attribute__((aligned(16)));  // a'[k][p_local]

    f32x4 acc2[4][8] = {};                // D[64k][128c] per wave (c0 = w*128)
    float asum_acc[2] = {0.f, 0.f};

    for (int ch = 0; ch < 5; ch++) {
        const int pch = pg * 160 + ch * 32;
        const int pw  = pch + pt * 16;

        // ---- GEMM1: wave -> D[16p][32k], K = 512 c. A direct from global x.
        const float* xq = x + (size_t)n * 512 * 1600 + (size_t)q * 8 * 1600 + pw + l15;
        const ushort* brow = Wb + (kh * 32 + l15) * 512 + q * 8;
        f32x4 acc1[2] = {};
        float ssp = 0.f;
        for (int kc = 0; kc < 16; kc++) {
            float fv[8];
            #pragma unroll
            for (int j = 0; j < 8; j++) fv[j] = xq[(size_t)(kc * 32 + j) * 1600];
            bf16x8 af;
            #pragma unroll
            for (int j = 0; j < 8; j++) {
                ssp = fmaf(fv[j], fv[j], ssp);     // fp32 sum of squares (row pw+l15)
                af[j] = (short)f2b(fv[j]);
            }
            #pragma unroll
            for (int nt = 0; nt < 2; nt++) {
                bf16x8 bw = *(const bf16x8*)(brow + nt * 16 * 512 + kc * 32);
                acc1[nt] = __builtin_amdgcn_mfma_f32_16x16x32_bf16(af, bw, acc1[nt], 0, 0, 0);
            }
        }
        ssp += __shfl_xor(ssp, 16, 64);
        ssp += __shfl_xor(ssp, 32, 64);
        float rn_l = 1.f / fmaxf(sqrtf(ssp), EPSF);
        float rnv[4];
        #pragma unroll
        for (int r = 0; r < 4; r++) rnv[r] = __shfl(rn_l, q * 4 + r, 64);  // rn for D-row q*4+r

        // ---- softmax over 64 k (2 nt in-lane x 16 l15 in-wave x 2 kh cross-wave)
        float v[2][4];
        float mx[4] = {-3.4e38f, -3.4e38f, -3.4e38f, -3.4e38f};
        #pragma unroll
        for (int nt = 0; nt < 2; nt++)
            #pragma unroll
            for (int r = 0; r < 4; r++) {
                v[nt][r] = acc1[nt][r] * rnv[r];
                mx[r] = fmaxf(mx[r], v[nt][r]);
            }
        #pragma unroll
        for (int s = 1; s <= 8; s <<= 1)
            #pragma unroll
            for (int r = 0; r < 4; r++) mx[r] = fmaxf(mx[r], __shfl_xor(mx[r], s, 64));
        if (l15 == 0) {
            #pragma unroll
            for (int r = 0; r < 4; r++) smx[kh][pt][q * 4 + r] = mx[r];
        }
        __syncthreads();
        float gmx[4];
        #pragma unroll
        for (int r = 0; r < 4; r++) gmx[r] = fmaxf(smx[0][pt][q * 4 + r], smx[1][pt][q * 4 + r]);
        float sm[4] = {0.f, 0.f, 0.f, 0.f};
        #pragma unroll
        for (int nt = 0; nt < 2; nt++)
            #pragma unroll
            for (int r = 0; r < 4; r++) { v[nt][r] = __expf(v[nt][r] - gmx[r]); sm[r] += v[nt][r]; }
        #pragma unroll
        for (int s = 1; s <= 8; s <<= 1)
            #pragma unroll
            for (int r = 0; r < 4; r++) sm[r] += __shfl_xor(sm[r], s, 64);
        if (l15 == 0) {
            #pragma unroll
            for (int r = 0; r < 4; r++) ssm[kh][pt][q * 4 + r] = sm[r];
        }
        __syncthreads();
        float inv[4];
        #pragma unroll
        for (int r = 0; r < 4; r++)
            inv[r] = 1.f / (ssm[0][pt][q * 4 + r] + ssm[1][pt][q * 4 + r]);

        // asum partials (accumulate across chunks in regs)
        #pragma unroll
        for (int nt = 0; nt < 2; nt++) {
            float t = v[nt][0] * inv[0] + v[nt][1] * inv[1] + v[nt][2] * inv[2] + v[nt][3] * inv[3];
            t += __shfl_xor(t, 16, 64);
            t += __shfl_xor(t, 32, 64);
            asum_acc[nt] += t;
        }

        // a' = a*rn -> bf16 -> as_[k][p_local]
        #pragma unroll
        for (int nt = 0; nt < 2; nt++)
            #pragma unroll
            for (int r = 0; r < 4; r++)
                as_[(kh * 32 + nt * 16 + l15) * ASTR + pt * 16 + q * 4 + r] =
                    f2b(v[nt][r] * inv[r] * rnv[r]);
        __syncthreads();

        // ---- GEMM2: acc2 += a'[k][p] * x[c][p], K = 32 p (one MFMA per tile pair)
        const int cw = w * 128;
        bf16x8 afr[4];
        #pragma unroll
        for (int mt = 0; mt < 4; mt++)
            afr[mt] = *(const bf16x8*)(as_ + (mt * 16 + l15) * ASTR + q * 8);
        #pragma unroll
        for (int ct = 0; ct < 8; ct++) {
            const float* xb = x + ((size_t)(n * 512 + cw + ct * 16 + l15)) * 1600 + pch + q * 8;
            float4 f0 = *(const float4*)(xb);
            float4 f1 = *(const float4*)(xb + 4);
            bf16x8 b;
            b[0] = (short)f2b(f0.x); b[1] = (short)f2b(f0.y);
            b[2] = (short)f2b(f0.z); b[3] = (short)f2b(f0.w);
            b[4] = (short)f2b(f1.x); b[5] = (short)f2b(f1.y);
            b[6] = (short)f2b(f1.z); b[7] = (short)f2b(f1.w);
            #pragma unroll
            for (int mt = 0; mt < 4; mt++)
                acc2[mt][ct] = __builtin_amdgcn_mfma_f32_16x16x32_bf16(afr[mt], b, acc2[mt][ct], 0, 0, 0);
        }
        __syncthreads();   // as_/smx/ssm reused next chunk
    }

    // ---- epilogue
    if (lane < 16) {
        #pragma unroll
        for (int nt = 0; nt < 2; nt++)
            atomicAdd(&asum[n * 64 + kh * 32 + nt * 16 + lane], asum_acc[nt]);
    }
    float* ob = out + (size_t)n * 32768 + w * 128 + l15;
    #pragma unroll
    for (int mt = 0; mt < 4; mt++)
        #pragma unroll
        for (int ct = 0; ct < 8; ct++)
            #pragma unroll
            for (int r = 0; r < 4; r++)
                atomicAdd(ob + (mt * 16 + q * 4 + r) * 512 + ct * 16, acc2[mt][ct][r]);
}

// ------------------------------------------------- K4a: rownorm2[n,k]
__global__ __launch_bounds__(256) void k4a_rownorm(const float* __restrict__ vraw,
                                                   const float* __restrict__ asum,
                                                   const float* __restrict__ cent,
                                                   float* __restrict__ rn2) {
    int row  = blockIdx.x * 4 + (threadIdx.x >> 6);
    int lane = threadIdx.x & 63;
    int k = row & 63;
    const float4* vp = (const float4*)(vraw + (size_t)row * 512 + lane * 8);
    const float4* cp = (const float4*)(cent + k * 512 + lane * 8);
    float as = asum[row];
    float4 v0 = vp[0], v1 = vp[1], c0 = cp[0], c1 = cp[1];
    float s = 0.f, t;
    t = v0.x - as * c0.x; s = fmaf(t, t, s);
    t = v0.y - as * c0.y; s = fmaf(t, t, s);
    t = v0.z - as * c0.z; s = fmaf(t, t, s);
    t = v0.w - as * c0.w; s = fmaf(t, t, s);
    t = v1.x - as * c1.x; s = fmaf(t, t, s);
    t = v1.y - as * c1.y; s = fmaf(t, t, s);
    t = v1.z - as * c1.z; s = fmaf(t, t, s);
    t = v1.w - as * c1.w; s = fmaf(t, t, s);
    #pragma unroll
    for (int off = 32; off > 0; off >>= 1) s += __shfl_down(s, off, 64);
    if (lane == 0) rn2[row] = s;
}

// ------------------------------------------------- K4b: gn[n]
__global__ __launch_bounds__(64) void k4b_gn(const float* __restrict__ rn2,
                                             float* __restrict__ gn) {
    int n = blockIdx.x, k = threadIdx.x;
    float t = rn2[n * 64 + k];
    float d = fmaxf(sqrtf(t), EPSF);
    float r = t / (d * d);
    #pragma unroll
    for (int off = 32; off > 0; off >>= 1) r += __shfl_down(r, off, 64);
    if (k == 0) gn[n] = fmaxf(sqrtf(r), EPSF);
}

// ------------------------------------------------- K4c: final normalize
__global__ __launch_bounds__(256) void k4c_final(float* __restrict__ vout,
                                                 const float* __restrict__ asum,
                                                 const float* __restrict__ cent,
                                                 const float* __restrict__ rn2,
                                                 const float* __restrict__ gn) {
    int gid = blockIdx.x * 256 + threadIdx.x;
    int idx4 = gid * 4;
    int row = idx4 >> 9;
    int n = row >> 6, k = row & 63, c = idx4 & 511;
    float4 v  = *(const float4*)(vout + idx4);
    float4 cv = *(const float4*)(cent + k * 512 + c);
    float as = asum[row];
    float inv = 1.f / (fmaxf(sqrtf(rn2[row]), EPSF) * gn[n]);
    v.x = (v.x - as * cv.x) * inv;
    v.y = (v.y - as * cv.y) * inv;
    v.z = (v.z - as * cv.z) * inv;
    v.w = (v.w - as * cv.w) * inv;
    *(float4*)(vout + idx4) = v;
}

// -------------------------------------------------
extern "C" void kernel_launch(void* const* d_in, const int* in_sizes, int n_in,
                              void* d_out, int out_size, void* d_ws, size_t ws_size,
                              hipStream_t stream) {
    const float* x    = (const float*)d_in[0];
    const float* W    = (const float*)d_in[1];
    const float* cent = (const float*)d_in[2];
    float* out = (float*)d_out;
    char* ws = (char*)d_ws;

    ushort* Wb   = (ushort*)(ws + 0);
    float*  asum = (float*)(ws + 65536);
    float*  rn2  = (float*)(ws + 81920);
    float*  gn   = (float*)(ws + 98304);

    hipMemsetAsync(asum, 0, 64 * 64 * sizeof(float), stream);
    hipMemsetAsync(d_out, 0, (size_t)out_size * sizeof(float), stream);

    hipLaunchKernelGGL(k0_wb,       dim3(128),    dim3(256), 0, stream, W, Wb);
    hipLaunchKernelGGL(k_fused2,    dim3(10, 64), dim3(256), 0, stream, x, Wb, out, asum);
    hipLaunchKernelGGL(k4a_rownorm, dim3(1024),   dim3(256), 0, stream, out, asum, cent, rn2);
    hipLaunchKernelGGL(k4b_gn,      dim3(64),     dim3(64),  0, stream, rn2, gn);
    hipLaunchKernelGGL(k4c_final,   dim3(2048),   dim3(256), 0, stream, out, asum, cent, rn2, gn);
}